// Round 13
// baseline (88.347 us; speedup 1.0000x reference)
//
#include <hip/hip_runtime.h>

// out[2048,64] = inputs[2048,2000] @ emb[2000,64] (fp32) via bf16 MFMA.
// SINGLE fused kernel: no ws, no atomics, no 2nd dispatch.
// Grid 256 blocks (1/CU): block owns 8 rows x all 64 cols x full K.
// K looped in 16 slabs of 128, double-buffered LDS, reg-staged loads
// issued before compute (latency hides under MFMA + LDS writes).
// MFMA tile is 16x16: A-rows 8..15 are zero (stored once), half-waste is
// negligible (MFMA ~3% of budget). C/D layout per m89.

#define Bn 2048
#define Vn 2000
#define Dn 64
#define MBLK 8
#define SLAB 128
#define NSLAB 16              // 16*128 = 2048 >= 2000 (padded with zeros)
#define LSTR 136              // bf16 row stride: 272B, 16B-aligned, 8-aligned shorts

typedef __attribute__((ext_vector_type(8))) short bf16x8;
typedef __attribute__((ext_vector_type(4))) float f32x4;

__device__ inline unsigned short bf16r(float x) {
    union { float f; unsigned u; } c; c.f = x;
    return (unsigned short)((c.u + 0x8000u) >> 16);   // round-half-up
}
__device__ inline unsigned pk2(float a, float b) {
    return ((unsigned)bf16r(b) << 16) | bf16r(a);     // little-endian pair
}

__global__ __launch_bounds__(256)
void embw_fused(const float* __restrict__ A, const float* __restrict__ E,
                float* __restrict__ out) {
    __shared__ unsigned short Al[2][16][LSTR];   // A slab, rows 8..15 == 0
    __shared__ unsigned short Et[2][Dn][LSTR];   // E slab transposed: Et[d][k]

    const int t    = threadIdx.x;
    const int lane = t & 63;
    const int w    = t >> 6;                     // wave 0..3 -> cols 16w..16w+15
    const int r0   = blockIdx.x * MBLK;

    // zero all of Al (rows 8..15 stay zero forever; 0..7 rewritten per slab)
    {
        unsigned* z = (unsigned*)Al;
        for (int i = t; i < (int)(sizeof(Al) / 4); i += 256) z[i] = 0;
    }
    __syncthreads();   // zero-writes vs stage-writes ordering

    // thread roles for staging
    const int arow = t >> 5;                     // 0..7  (A row)
    const int ac4  = t & 31;                     // A float4 col (k/4)
    const int ec4  = t & 15;                     // E float4 col (d/4)
    const int ekr  = t >> 4;                     // 0..15 (k row base)
    const float* Arow = A + (size_t)(r0 + arow) * Vn;

    f32x4 acc = {0.f, 0.f, 0.f, 0.f};
    const int fr = lane & 15;
    const int fk = (lane >> 4) * 8;

    // ---- prologue: stage slab 0 into buf 0 ----
    float4 ra; float4 re[8];
    {
        ra = *(const float4*)&Arow[ac4 * 4];     // k<=124 < Vn always
#pragma unroll
        for (int j = 0; j < 8; ++j)
            re[j] = *(const float4*)&E[(size_t)(ekr + 16 * j) * Dn + ec4 * 4];
        *(uint2*)&Al[0][arow][ac4 * 4] = make_uint2(pk2(ra.x, ra.y), pk2(ra.z, ra.w));
#pragma unroll
        for (int j = 0; j < 8; ++j) {
            const int k = ekr + 16 * j;
            Et[0][ec4 * 4 + 0][k] = bf16r(re[j].x);
            Et[0][ec4 * 4 + 1][k] = bf16r(re[j].y);
            Et[0][ec4 * 4 + 2][k] = bf16r(re[j].z);
            Et[0][ec4 * 4 + 3][k] = bf16r(re[j].w);
        }
    }
    __syncthreads();

#pragma unroll 1
    for (int s = 0; s < NSLAB; ++s) {
        const int cur = s & 1;
        // issue next-slab global loads (latency overlaps compute below)
        if (s + 1 < NSLAB) {
            const int k0n = (s + 1) * SLAB;
            const int gka = k0n + ac4 * 4;       // multiple of 4; +3 in-bounds iff < Vn
            ra = (gka < Vn) ? *(const float4*)&Arow[gka] : make_float4(0.f, 0.f, 0.f, 0.f);
#pragma unroll
            for (int j = 0; j < 8; ++j) {
                const int gk = k0n + ekr + 16 * j;
                re[j] = (gk < Vn) ? *(const float4*)&E[(size_t)gk * Dn + ec4 * 4]
                                  : make_float4(0.f, 0.f, 0.f, 0.f);
            }
        }
        // compute current slab: 4 K-steps of 16x16x32
#pragma unroll
        for (int ks = 0; ks < SLAB / 32; ++ks) {
            const int kb = ks * 32 + fk;
            bf16x8 af = *(const bf16x8*)&Al[cur][fr][kb];
            bf16x8 bfv = *(const bf16x8*)&Et[cur][w * 16 + fr][kb];
            acc = __builtin_amdgcn_mfma_f32_16x16x32_bf16(af, bfv, acc, 0, 0, 0);
        }
        // write next slab into the other buffer
        if (s + 1 < NSLAB) {
            const int nxt = cur ^ 1;
            *(uint2*)&Al[nxt][arow][ac4 * 4] = make_uint2(pk2(ra.x, ra.y), pk2(ra.z, ra.w));
#pragma unroll
            for (int j = 0; j < 8; ++j) {
                const int k = ekr + 16 * j;
                Et[nxt][ec4 * 4 + 0][k] = bf16r(re[j].x);
                Et[nxt][ec4 * 4 + 1][k] = bf16r(re[j].y);
                Et[nxt][ec4 * 4 + 2][k] = bf16r(re[j].z);
                Et[nxt][ec4 * 4 + 3][k] = bf16r(re[j].w);
            }
        }
        __syncthreads();
    }

    // ---- store: C/D col=lane&15, row=(lane>>4)*4+q; only rows 0..7 real ----
    if (lane < 32) {
        float* op = out + (size_t)(r0 + (lane >> 4) * 4) * Dn + w * 16 + fr;
#pragma unroll
        for (int q = 0; q < 4; ++q)
            op[(size_t)q * Dn] = acc[q];
    }
}

extern "C" void kernel_launch(void* const* d_in, const int* in_sizes, int n_in,
                              void* d_out, int out_size, void* d_ws, size_t ws_size,
                              hipStream_t stream) {
    const float* in  = (const float*)d_in[0];   // (2048, 2000) fp32
    const float* emb = (const float*)d_in[1];   // (2000, 64)  fp32
    float* out = (float*)d_out;                 // (2048, 64)  fp32

    embw_fused<<<Bn / MBLK, 256, 0, stream>>>(in, emb, out);   // 256 blocks
}

// Round 14
// 74.284 us; speedup vs baseline: 1.1893x; 1.1893x over previous
//
#include <hip/hip_runtime.h>

// out[2048,64] = inputs[2048,2000] @ emb[2000,64] (fp32) via bf16 MFMA.
// K0: pre-pack E into MFMA B-fragment order (bf16, 256 KB in ws):
//     Efrag[ks][ct][lane] = 16B = E[ks*32+(lane>>4)*8+j][ct*16+(lane&15)], j=0..7
// K1: R12 grid (32 m-blocks x 16 k-chunks, 512 blocks): A staged in LDS
//     (coalesced float4 -> bf16), B-frags loaded DIRECT from Efrag
//     (1 KB/wave coalesced, L2-hot) -- E^T LDS staging eliminated.
// K2: reduce 16 partials -> out.

#define Bn 2048
#define Vn 2000
#define Dn 64
#define KCH 16
#define KBLK 128
#define MBLK 64
#define LSTR 136            // bf16 LDS row stride (R12-validated)
#define NKS 64              // total K-steps: 2048/32
#define EFRAG_FLOATS 65536  // 256 KB / 4

typedef __attribute__((ext_vector_type(8))) short bf16x8;
typedef __attribute__((ext_vector_type(4))) float f32x4;

__device__ inline unsigned short bf16r(float x) {
    union { float f; unsigned u; } c; c.f = x;
    return (unsigned short)((c.u + 0x8000u) >> 16);
}

// ---- K0: E (2000x64 f32) -> Efrag[NKS][4][64] x 16B ----
__global__ __launch_bounds__(256)
void efrag_k(const float* __restrict__ E, uint4* __restrict__ ef) {
    const int ks   = blockIdx.x;            // 0..63
    const int ct   = threadIdx.x >> 6;      // 0..3
    const int lane = threadIdx.x & 63;
    const int d    = ct * 16 + (lane & 15);
    const int kb   = ks * 32 + (lane >> 4) * 8;
    unsigned short h[8];
#pragma unroll
    for (int j = 0; j < 8; ++j) {
        const int gk = kb + j;
        h[j] = (gk < Vn) ? bf16r(E[(size_t)gk * Dn + d]) : (unsigned short)0;
    }
    uint4 v;
    v.x = (unsigned)h[0] | ((unsigned)h[1] << 16);
    v.y = (unsigned)h[2] | ((unsigned)h[3] << 16);
    v.z = (unsigned)h[4] | ((unsigned)h[5] << 16);
    v.w = (unsigned)h[6] | ((unsigned)h[7] << 16);
    ef[((size_t)ks * 4 + ct) * 64 + lane] = v;
}

// ---- K1: GEMM partials ----
__global__ __launch_bounds__(256)
void embw_mfma(const float* __restrict__ A, const bf16x8* __restrict__ ef,
               float* __restrict__ part) {
    __shared__ unsigned short Al[MBLK][LSTR];

    const int t    = threadIdx.x;
    const int lane = t & 63;
    const int w    = t >> 6;
    const int kc   = blockIdx.x >> 5;
    const int mblk = blockIdx.x & 31;
    const int m0   = mblk * MBLK;
    const int k0   = kc * KBLK;

    // stage A: 64 rows x 128 k, coalesced float4, fp32 -> bf16 (R12 code)
    {
        const int rs = t >> 5;
        const int c4 = t & 31;
        const int gk = k0 + c4 * 4;
        const bool real = (gk < Vn);         // Vn%4==0: aligned cut
#pragma unroll
        for (int s = 0; s < 8; ++s) {
            const int row = s * 8 + rs;
            float4 v = make_float4(0.f, 0.f, 0.f, 0.f);
            if (real)
                v = *(const float4*)&A[(size_t)(m0 + row) * Vn + gk];
            unsigned lo = ((unsigned)bf16r(v.y) << 16) | bf16r(v.x);
            unsigned hi = ((unsigned)bf16r(v.w) << 16) | bf16r(v.z);
            *(uint2*)&Al[row][c4 * 4] = make_uint2(lo, hi);
        }
    }
    __syncthreads();

    const int fr = lane & 15;
    const int fk = (lane >> 4) * 8;
    f32x4 acc0 = {0.f,0.f,0.f,0.f}, acc1 = {0.f,0.f,0.f,0.f};
    f32x4 acc2 = {0.f,0.f,0.f,0.f}, acc3 = {0.f,0.f,0.f,0.f};

#pragma unroll
    for (int ks = 0; ks < KBLK / 32; ++ks) {
        const int ksg = kc * 4 + ks;                     // global K-step
        const size_t eb = ((size_t)ksg * 4) * 64 + lane; // frag base
        bf16x8 af = *(const bf16x8*)&Al[w * 16 + fr][ks * 32 + fk];
        bf16x8 b0 = ef[eb +   0];
        bf16x8 b1 = ef[eb +  64];
        bf16x8 b2 = ef[eb + 128];
        bf16x8 b3 = ef[eb + 192];
        acc0 = __builtin_amdgcn_mfma_f32_16x16x32_bf16(af, b0, acc0, 0, 0, 0);
        acc1 = __builtin_amdgcn_mfma_f32_16x16x32_bf16(af, b1, acc1, 0, 0, 0);
        acc2 = __builtin_amdgcn_mfma_f32_16x16x32_bf16(af, b2, acc2, 0, 0, 0);
        acc3 = __builtin_amdgcn_mfma_f32_16x16x32_bf16(af, b3, acc3, 0, 0, 0);
    }

    // partials: C/D col=lane&15, row=(lane>>4)*4+q (validated R12)
    float* pp = part + ((size_t)kc * Bn + m0 + w * 16 + (lane >> 4) * 4) * Dn + fr;
#pragma unroll
    for (int q = 0; q < 4; ++q) {
        pp[(size_t)q * Dn +  0] = acc0[q];
        pp[(size_t)q * Dn + 16] = acc1[q];
        pp[(size_t)q * Dn + 32] = acc2[q];
        pp[(size_t)q * Dn + 48] = acc3[q];
    }
}

// ---- K2: reduce 16 partials ----
__global__ __launch_bounds__(256)
void embw_reduce(const float* __restrict__ part, float* __restrict__ out) {
    const int i = blockIdx.x * 256 + threadIdx.x;
    const float4* p = (const float4*)part;
    float4 s = p[i];
#pragma unroll
    for (int c = 1; c < KCH; ++c) {
        float4 tv = p[(size_t)c * (Bn * Dn / 4) + i];
        s.x += tv.x; s.y += tv.y; s.z += tv.z; s.w += tv.w;
    }
    ((float4*)out)[i] = s;
}

extern "C" void kernel_launch(void* const* d_in, const int* in_sizes, int n_in,
                              void* d_out, int out_size, void* d_ws, size_t ws_size,
                              hipStream_t stream) {
    const float* in  = (const float*)d_in[0];   // (2048, 2000) fp32
    const float* emb = (const float*)d_in[1];   // (2000, 64)  fp32
    float* out = (float*)d_out;                 // (2048, 64)  fp32

    uint4* efrag = (uint4*)d_ws;                              // 256 KB
    float* part  = (float*)d_ws + EFRAG_FLOATS;               // 8 MB

    efrag_k<<<NKS, 256, 0, stream>>>(emb, efrag);
    embw_mfma<<<32 * KCH, 256, 0, stream>>>(in, (const bf16x8*)efrag, part);
    embw_reduce<<<(Bn * Dn / 4) / 256, 256, 0, stream>>>(part, out);
}